// Round 9
// baseline (580.249 us; speedup 1.0000x reference)
//
#include <hip/hip_runtime.h>

#define NN 50000
#define NE 1600000
#define EP (NE + NN)   // edges + self loops
#define IN_DIM 256
#define HIDD 64
#define NCLS 10
#define NB_SCAN ((NN + 255) / 256)   // 196 blocks for the degree scan

typedef unsigned short u16;
typedef short bf16x8 __attribute__((ext_vector_type(8)));
typedef float f32x4 __attribute__((ext_vector_type(4)));

__device__ __forceinline__ float b2f(u16 v) { return __uint_as_float(((unsigned)v) << 16); }
__device__ __forceinline__ u16 f2b(float f) {
    unsigned u = __float_as_uint(f);
    unsigned r = (u + 0x7FFFu + ((u >> 16) & 1u)) >> 16;
    return (u16)r;
}

// ---- edge_index dtype autodetect: int64 => all odd int32 words are 0 (ids < 2^31) ----
__global__ void detect_mode_k(const int* __restrict__ ei, int* __restrict__ mode) {
    int t = threadIdx.x;  // 64 threads
    int nz = 0;
#pragma unroll
    for (int k = 0; k < 4; ++k) {
        int i = t * 4 + k;
        if (ei[2 * i + 1] != 0) nz = 1;
    }
    unsigned long long b = __ballot(nz);
    if (t == 0) *mode = (b == 0ULL) ? 1 : 0;   // 1 = int64 layout
}

__device__ __forceinline__ void load_edge(const int* __restrict__ ei, int m, int g,
                                          int& s, int& d) {
    if (g < NE) {
        if (m) { s = ei[2 * (size_t)g]; d = ei[2 * ((size_t)NE + g)]; }
        else   { s = ei[g];             d = ei[NE + g]; }
    } else {
        s = d = g - NE;  // self loop
    }
    s = s < 0 ? 0 : (s >= NN ? NN - 1 : s);
    d = d < 0 ? 0 : (d >= NN ? NN - 1 : d);
}

// ---- dtype converts ----
__global__ __launch_bounds__(256) void xcvt_k(const float* __restrict__ x,
                                              u16* __restrict__ xb, int total4) {
    int i = blockIdx.x * blockDim.x + threadIdx.x;
    if (i >= total4) return;
    float4 v = *(const float4*)(x + (size_t)i * 4);
    ushort4 o;
    o.x = f2b(v.x); o.y = f2b(v.y); o.z = f2b(v.z); o.w = f2b(v.w);
    *(ushort4*)(xb + (size_t)i * 4) = o;
}

// Wt[n][k] = bf16(W[k][n]);  W is K x N row-major
__global__ __launch_bounds__(256) void wcvt_k(const float* __restrict__ W,
                                              u16* __restrict__ Wt, int K, int N) {
    int idx = blockIdx.x * blockDim.x + threadIdx.x;
    if (idx >= K * N) return;
    int n = idx / K, k = idx - n * K;
    Wt[idx] = f2b(W[(size_t)k * N + n]);
}

// ---- CSR build ----
__global__ __launch_bounds__(256) void deg_count_k(const int* __restrict__ ei,
                                                   const int* __restrict__ mode,
                                                   int* __restrict__ deg) {
    int g = blockIdx.x * blockDim.x + threadIdx.x;
    if (g >= EP) return;
    int m = *mode, s, d;
    load_edge(ei, m, g, s, d);
    atomicAdd(&deg[d], 1);
}

__global__ __launch_bounds__(256) void scan1_k(const int* __restrict__ deg,
                                               int* __restrict__ excl,
                                               int* __restrict__ bsums) {
    __shared__ int sh[256];
    int t = threadIdx.x, b = blockIdx.x, i = b * 256 + t;
    int v = (i < NN) ? deg[i] : 0;
    sh[t] = v;
    __syncthreads();
    for (int off = 1; off < 256; off <<= 1) {
        int x = (t >= off) ? sh[t - off] : 0;
        __syncthreads();
        sh[t] += x;
        __syncthreads();
    }
    if (i < NN) excl[i] = sh[t] - v;
    if (t == 255) bsums[b] = sh[t];
}

__global__ __launch_bounds__(256) void scan2_k(int* __restrict__ bsums) {
    __shared__ int sh[256];
    int t = threadIdx.x;
    int v = (t < NB_SCAN) ? bsums[t] : 0;
    sh[t] = v;
    __syncthreads();
    for (int off = 1; off < 256; off <<= 1) {
        int x = (t >= off) ? sh[t - off] : 0;
        __syncthreads();
        sh[t] += x;
        __syncthreads();
    }
    if (t < NB_SCAN) bsums[t] = sh[t] - v;  // exclusive
}

// row_ptr and cursor both get the exclusive scan result
__global__ __launch_bounds__(256) void scan3_k(const int* __restrict__ excl,
                                               const int* __restrict__ bsums,
                                               int* __restrict__ row_ptr,
                                               int* __restrict__ cursor) {
    int t = threadIdx.x, b = blockIdx.x, i = b * 256 + t;
    if (i < NN) {
        int v = excl[i] + bsums[b];
        row_ptr[i] = v;
        cursor[i] = v;
    }
    if (i == 0) row_ptr[NN] = EP;
}

// cursor pre-initialized to row_ptr => absolute position, no row_ptr read
__global__ __launch_bounds__(256) void scatter_k(const int* __restrict__ ei,
                                                 const int* __restrict__ mode,
                                                 int* __restrict__ cursor,
                                                 int* __restrict__ csr_src) {
    int g = blockIdx.x * blockDim.x + threadIdx.x;
    if (g >= EP) return;
    int m = *mode, s, d;
    load_edge(ei, m, g, s, d);
    int pos = atomicAdd(&cursor[d], 1);
    csr_src[pos] = s;
}

// ---- MFMA GEMM: C[M=NN][N] bf16 = A[NN][K] bf16 @ Wt[N][K] bf16 (f32 acc) ----
template <int K, int N>
__global__ __launch_bounds__(256) void gemm_mfma_k(
    const u16* __restrict__ A, const u16* __restrict__ Wt, u16* __restrict__ C) {
    constexpr int NT = N / 16, KS = K / 32;
    const int wave = threadIdx.x >> 6, lane = threadIdx.x & 63;
    const int quad = lane >> 4, l15 = lane & 15;
    const int m0 = blockIdx.x * 64 + wave * 16;
    int rowA = m0 + l15;
    if (rowA >= NN) rowA = NN - 1;
    const u16* aptr = A + (size_t)rowA * K + quad * 8;
    const u16* bptr = Wt + (size_t)l15 * K + quad * 8;
    f32x4 acc[NT] = {};
#pragma unroll
    for (int ks = 0; ks < KS; ++ks) {
        bf16x8 af = *(const bf16x8*)(aptr + ks * 32);
        bf16x8 bf[NT];
#pragma unroll
        for (int nt = 0; nt < NT; ++nt)
            bf[nt] = *(const bf16x8*)(bptr + (size_t)nt * 16 * K + ks * 32);
#pragma unroll
        for (int nt = 0; nt < NT; ++nt)
            acc[nt] = __builtin_amdgcn_mfma_f32_16x16x32_bf16(af, bf[nt], acc[nt], 0, 0, 0);
    }
#pragma unroll
    for (int nt = 0; nt < NT; ++nt) {
#pragma unroll
        for (int reg = 0; reg < 4; ++reg) {
            int row = m0 + quad * 4 + reg;
            if (row < NN) C[(size_t)row * N + nt * 16 + l15] = f2b(acc[nt][reg]);
        }
    }
}

// ---- per-node attention scores (bf16 h): one 64-lane wave per head ----
__global__ void att_scores_k(const u16* __restrict__ h, const float* __restrict__ asrc,
                             const float* __restrict__ adst, float* __restrict__ a_s,
                             float* __restrict__ a_d, int H) {
    int n = blockIdx.x, tid = threadIdx.x;  // blockDim.x == H*64
    float v = b2f(h[(size_t)n * blockDim.x + tid]);
    float ps = v * asrc[tid];
    float pd = v * adst[tid];
#pragma unroll
    for (int off = 32; off; off >>= 1) {
        ps += __shfl_down(ps, off);
        pd += __shfl_down(pd, off);
    }
    if ((tid & 63) == 0) {
        int hh = tid >> 6;
        a_s[(size_t)n * H + hh] = ps;
        a_d[(size_t)n * H + hh] = pd;
    }
}

// ---- fused gather: TWO waves per node (each half the edges), LDS combine ----
// Per wave: lane-parallel exp over its 64-edge chunks, JB-batched j-loop
// (8 independent h-row loads in flight). Partials combined in LDS; the
// sub-0 wave runs the epilogue (bias+ELU, optional fused linear head).
template <int CH, int H, bool HEAD>
__global__ __launch_bounds__(256) void gat_gather_k(
    const int* __restrict__ row_ptr, const int* __restrict__ csr_src,
    const float* __restrict__ a_s, const float* __restrict__ a_d,
    const u16* __restrict__ h, const float* __restrict__ bias,
    u16* __restrict__ outg, const float* __restrict__ Wl,
    const float* __restrict__ bl, float* __restrict__ outh) {
    constexpr int VEC = CH / 64;
    constexpr int JB = 8;  // loads in flight per wave
    __shared__ float sacc[4][CH];
    __shared__ float sden[4][2];
    const int wave = threadIdx.x >> 6;
    const int lane = threadIdx.x & 63;
    const int n = blockIdx.x * 2 + (wave >> 1);  // 2 nodes per block, exact grid
    const int sub = wave & 1;
    const bool hi = (VEC == 2) ? (lane >= 32) : false;
    const u16* hlane = h + lane * VEC;

    int r0 = row_ptr[n], r1 = row_ptr[n + 1];
    int half = (r1 - r0 + 1) >> 1;
    int b0 = sub ? r0 + half : r0;
    int b1 = sub ? r1 : r0 + half;

    float adn[H];
#pragma unroll
    for (int hh = 0; hh < H; ++hh) adn[hh] = a_d[n * H + hh];

    float dh0 = 0.f, dh1 = 0.f;
    float acc[VEC];
#pragma unroll
    for (int v = 0; v < VEC; ++v) acc[v] = 0.f;

    for (int base = b0; base < b1; base += 64) {
        int cnt = min(64, b1 - base);
        int idx = base + lane;
        bool act = idx < b1;
        int sl = act ? csr_src[idx] : 0;
        float exl0 = 0.f, exl1 = 0.f;
        {
            float e = a_s[sl * H + 0] + adn[0];
            e = e > 0.f ? e : 0.2f * e;
            e = fminf(e, 60.f);
            exl0 = act ? __expf(e) : 0.f;
            dh0 += exl0;
        }
        if (H == 2) {
            float e = a_s[sl * H + 1] + adn[1];
            e = e > 0.f ? e : 0.2f * e;
            e = fminf(e, 60.f);
            exl1 = act ? __expf(e) : 0.f;
            dh1 += exl1;
        }
        for (int j0 = 0; j0 < cnt; j0 += JB) {
            int ss[JB];
            float exv[JB];
#pragma unroll
            for (int i = 0; i < JB; ++i) {
                int j = j0 + i;
                ss[i] = __shfl(sl, j);
                if (H == 1) {
                    exv[i] = __shfl(exl0, j);
                } else {
                    float e0 = __shfl(exl0, j);
                    float e1 = __shfl(exl1, j);
                    exv[i] = hi ? e1 : e0;
                }
            }
            if (VEC == 2) {
                ushort2 hv[JB];
#pragma unroll
                for (int i = 0; i < JB; ++i)
                    hv[i] = *(const ushort2*)(hlane + (size_t)ss[i] * CH);
#pragma unroll
                for (int i = 0; i < JB; ++i) {
                    acc[0] += exv[i] * b2f(hv[i].x);
                    acc[1] += exv[i] * b2f(hv[i].y);
                }
            } else {
                u16 hv[JB];
#pragma unroll
                for (int i = 0; i < JB; ++i)
                    hv[i] = hlane[(size_t)ss[i] * CH];
#pragma unroll
                for (int i = 0; i < JB; ++i)
                    acc[0] += exv[i] * b2f(hv[i]);
            }
        }
    }

    // per-wave butterfly for the denominator partials
#pragma unroll
    for (int off = 32; off; off >>= 1) dh0 += __shfl_xor(dh0, off);
    if (H == 2) {
#pragma unroll
        for (int off = 32; off; off >>= 1) dh1 += __shfl_xor(dh1, off);
    }

    // stash partials in LDS
#pragma unroll
    for (int v = 0; v < VEC; ++v) sacc[wave][lane * VEC + v] = acc[v];
    if (lane == 0) {
        sden[wave][0] = dh0;
        sden[wave][1] = (H == 2) ? dh1 : 0.f;
    }
    __syncthreads();
    if (sub) return;  // partner wave done

    float dn0 = sden[wave][0] + sden[wave + 1][0];
    float dn1 = sden[wave][1] + sden[wave + 1][1];

    if (VEC == 2) {
        int c = lane * 2;
        float a0 = sacc[wave][c] + sacc[wave + 1][c];
        float a1 = sacc[wave][c + 1] + sacc[wave + 1][c + 1];
        float dn = hi ? dn1 : dn0;
        float2 bv = *(const float2*)(bias + c);
        float v0 = a0 / dn + bv.x;
        float v1 = a1 / dn + bv.y;
        v0 = v0 > 0.f ? v0 : expm1f(v0);
        v1 = v1 > 0.f ? v1 : expm1f(v1);
        ushort2 ov;
        ov.x = f2b(v0); ov.y = f2b(v1);
        *(ushort2*)(outg + (size_t)n * CH + c) = ov;
    } else {
        float a0 = sacc[wave][lane] + sacc[wave + 1][lane];
        float v0 = a0 / dn0 + bias[lane];
        v0 = v0 > 0.f ? v0 : expm1f(v0);
        if (HEAD) {
#pragma unroll
            for (int cls = 0; cls < NCLS; ++cls) {
                float p = v0 * Wl[lane * NCLS + cls];
#pragma unroll
                for (int off = 32; off; off >>= 1) p += __shfl_xor(p, off);
                if (lane == cls) outh[(size_t)n * NCLS + cls] = p + bl[cls];
            }
        } else {
            outg[(size_t)n * CH + lane] = f2b(v0);
        }
    }
}

extern "C" void kernel_launch(void* const* d_in, const int* in_sizes, int n_in,
                              void* d_out, int out_size, void* d_ws, size_t ws_size,
                              hipStream_t stream) {
    const float* x   = (const float*)d_in[0];
    const int*   ei  = (const int*)d_in[1];
    const float* W1  = (const float*)d_in[2];
    const float* as1 = (const float*)d_in[3];
    const float* ad1 = (const float*)d_in[4];
    const float* b1  = (const float*)d_in[5];
    const float* W2  = (const float*)d_in[6];
    const float* as2 = (const float*)d_in[7];
    const float* ad2 = (const float*)d_in[8];
    const float* b2  = (const float*)d_in[9];
    const float* Wl  = (const float*)d_in[10];
    const float* bl  = (const float*)d_in[11];
    float* out = (float*)d_out;

    // ---- workspace layout: ~60 MB ----
    float* ws = (float*)d_ws;
    size_t o = 0;
    u16* xb  = (u16*)(ws + o); o += (size_t)NN * 128;   // bf16 x [NN][256]
    u16* hb  = (u16*)(ws + o); o += (size_t)NN * 64;    // bf16 h1[NN][128] / h2[NN][64]
    u16* g1  = (u16*)(ws + o); o += (size_t)NN * 64;    // bf16 g1 [NN][128]
    u16* w1t = (u16*)(ws + o); o += 128 * 256 / 2;      // bf16 W1^T [128][256]
    u16* w2t = (u16*)(ws + o); o += 64 * 128 / 2;       // bf16 W2^T [64][128]
    float* a_s = ws + o;       o += (size_t)NN * 2;
    float* a_d = ws + o;       o += (size_t)NN * 2;
    int* ints = (int*)(ws + o);
    size_t io = 0;
    int* deg     = ints + io; io += NN;
    int* cursor  = ints + io; io += NN;
    int* excl    = ints + io; io += NN;
    int* bsums   = ints + io; io += 256;
    int* row_ptr = ints + io; io += NN + 1;
    int* csr_src = ints + io; io += EP;
    int* mode    = ints + io; io += 1;

    detect_mode_k<<<1, 64, 0, stream>>>(ei, mode);

    // ---- converts ----
    xcvt_k<<<((size_t)NN * 64 + 255) / 256, 256, 0, stream>>>(x, xb, NN * 64);
    wcvt_k<<<(256 * 128 + 255) / 256, 256, 0, stream>>>(W1, w1t, 256, 128);
    wcvt_k<<<(128 * 64 + 255) / 256, 256, 0, stream>>>(W2, w2t, 128, 64);

    // ---- CSR of incoming edges (shared by both layers) ----
    hipMemsetAsync(deg, 0, NN * sizeof(int), stream);
    deg_count_k<<<(EP + 255) / 256, 256, 0, stream>>>(ei, mode, deg);
    scan1_k<<<NB_SCAN, 256, 0, stream>>>(deg, excl, bsums);
    scan2_k<<<1, 256, 0, stream>>>(bsums);
    scan3_k<<<NB_SCAN, 256, 0, stream>>>(excl, bsums, row_ptr, cursor);
    scatter_k<<<(EP + 255) / 256, 256, 0, stream>>>(ei, mode, cursor, csr_src);

    const int gatherBlocks = NN / 2;   // 2 nodes per 256-thread block (2 waves/node)
    const int gemmBlocks = (NN + 63) / 64;

    // ---- layer 1: GATConv(256 -> 64, heads=2, concat) + ELU ----
    gemm_mfma_k<256, 128><<<gemmBlocks, 256, 0, stream>>>(xb, w1t, hb);   // h1 bf16
    att_scores_k<<<NN, 128, 0, stream>>>(hb, as1, ad1, a_s, a_d, 2);
    gat_gather_k<128, 2, false><<<gatherBlocks, 256, 0, stream>>>(
        row_ptr, csr_src, a_s, a_d, hb, b1, g1, nullptr, nullptr, nullptr);

    // ---- layer 2: GATConv(128 -> 64, heads=1) + ELU + fused head ----
    gemm_mfma_k<128, 64><<<gemmBlocks, 256, 0, stream>>>(g1, w2t, hb);    // h2 bf16
    att_scores_k<<<NN, 64, 0, stream>>>(hb, as2, ad2, a_s, a_d, 1);
    gat_gather_k<64, 1, true><<<gatherBlocks, 256, 0, stream>>>(
        row_ptr, csr_src, a_s, a_d, hb, b2, nullptr, Wl, bl, out);
}

// Round 10
// 411.431 us; speedup vs baseline: 1.4103x; 1.4103x over previous
//
#include <hip/hip_runtime.h>

#define NN 50000
#define NE 1600000
#define EP (NE + NN)   // edges + self loops
#define IN_DIM 256
#define HIDD 64
#define NCLS 10
#define NBKT 196                       // destination buckets: d >> 8
#define EPB 8192                       // edges per partition block
#define NPB ((EP + EPB - 1) / EPB)     // 202 partition blocks

typedef unsigned short u16;
typedef short bf16x8 __attribute__((ext_vector_type(8)));
typedef float f32x4 __attribute__((ext_vector_type(4)));

__device__ __forceinline__ float b2f(u16 v) { return __uint_as_float(((unsigned)v) << 16); }
__device__ __forceinline__ u16 f2b(float f) {
    unsigned u = __float_as_uint(f);
    unsigned r = (u + 0x7FFFu + ((u >> 16) & 1u)) >> 16;
    return (u16)r;
}

// ---- edge_index dtype autodetect: int64 => all odd int32 words are 0 (ids < 2^31) ----
__global__ void detect_mode_k(const int* __restrict__ ei, int* __restrict__ mode) {
    int t = threadIdx.x;  // 64 threads
    int nz = 0;
#pragma unroll
    for (int k = 0; k < 4; ++k) {
        int i = t * 4 + k;
        if (ei[2 * i + 1] != 0) nz = 1;
    }
    unsigned long long b = __ballot(nz);
    if (t == 0) *mode = (b == 0ULL) ? 1 : 0;   // 1 = int64 layout
}

__device__ __forceinline__ void load_edge(const int* __restrict__ ei, int m, int g,
                                          int& s, int& d) {
    if (g < NE) {
        if (m) { s = ei[2 * (size_t)g]; d = ei[2 * ((size_t)NE + g)]; }
        else   { s = ei[g];             d = ei[NE + g]; }
    } else {
        s = d = g - NE;  // self loop
    }
    s = s < 0 ? 0 : (s >= NN ? NN - 1 : s);
    d = d < 0 ? 0 : (d >= NN ? NN - 1 : d);
}

// ---- dtype converts ----
__global__ __launch_bounds__(256) void xcvt_k(const float* __restrict__ x,
                                              u16* __restrict__ xb, int total4) {
    int i = blockIdx.x * blockDim.x + threadIdx.x;
    if (i >= total4) return;
    float4 v = *(const float4*)(x + (size_t)i * 4);
    ushort4 o;
    o.x = f2b(v.x); o.y = f2b(v.y); o.z = f2b(v.z); o.w = f2b(v.w);
    *(ushort4*)(xb + (size_t)i * 4) = o;
}

// Wt[n][k] = bf16(W[k][n]);  W is K x N row-major
__global__ __launch_bounds__(256) void wcvt_k(const float* __restrict__ W,
                                              u16* __restrict__ Wt, int K, int N) {
    int idx = blockIdx.x * blockDim.x + threadIdx.x;
    if (idx >= K * N) return;
    int n = idx / K, k = idx - n * K;
    Wt[idx] = f2b(W[(size_t)k * N + n]);
}

// ---- radix CSR build: pass A — per-bucket counts ----
__global__ __launch_bounds__(256) void bktcount_k(const int* __restrict__ ei,
                                                  const int* __restrict__ mode,
                                                  int* __restrict__ gcnt) {
    __shared__ int hist[NBKT];
    int t = threadIdx.x;
    for (int i = t; i < NBKT; i += 256) hist[i] = 0;
    __syncthreads();
    int m = *mode;
    int g0 = blockIdx.x * EPB;
    int gend = min(g0 + EPB, EP);
    for (int g = g0 + t; g < gend; g += 256) {
        int s, d;
        load_edge(ei, m, g, s, d);
        atomicAdd(&hist[d >> 8], 1);
    }
    __syncthreads();
    for (int i = t; i < NBKT; i += 256)
        if (hist[i]) atomicAdd(&gcnt[i], hist[i]);
}

// ---- pass A2 — exclusive scan of bucket counts ----
__global__ __launch_bounds__(256) void bktscan_k(const int* __restrict__ gcnt,
                                                 int* __restrict__ bkt_base,
                                                 int* __restrict__ gcursor) {
    __shared__ int sh[256];
    int t = threadIdx.x;
    int v = (t < NBKT) ? gcnt[t] : 0;
    sh[t] = v;
    __syncthreads();
    for (int off = 1; off < 256; off <<= 1) {
        int x = (t >= off) ? sh[t - off] : 0;
        __syncthreads();
        sh[t] += x;
        __syncthreads();
    }
    if (t < NBKT) {
        int b = sh[t] - v;
        bkt_base[t] = b;
        gcursor[t] = b;
    }
    if (t == 0) bkt_base[NBKT] = EP;
}

// ---- pass B — partition edges into bucket runs (packed (s<<8)|(d&255)) ----
__global__ __launch_bounds__(256) void partition_k(const int* __restrict__ ei,
                                                   const int* __restrict__ mode,
                                                   int* __restrict__ gcursor,
                                                   unsigned* __restrict__ bbuf) {
    __shared__ int hist[NBKT], base[NBKT], cur[NBKT];
    int t = threadIdx.x;
    for (int i = t; i < NBKT; i += 256) hist[i] = 0;
    __syncthreads();
    int m = *mode;
    int g0 = blockIdx.x * EPB;
    int gend = min(g0 + EPB, EP);
    for (int g = g0 + t; g < gend; g += 256) {
        int s, d;
        load_edge(ei, m, g, s, d);
        atomicAdd(&hist[d >> 8], 1);
    }
    __syncthreads();
    for (int i = t; i < NBKT; i += 256) {
        base[i] = hist[i] ? atomicAdd(&gcursor[i], hist[i]) : 0;
        cur[i] = 0;
    }
    __syncthreads();
    for (int g = g0 + t; g < gend; g += 256) {
        int s, d;
        load_edge(ei, m, g, s, d);
        int b = d >> 8;
        int r = atomicAdd(&cur[b], 1);
        bbuf[base[b] + r] = ((unsigned)s << 8) | (unsigned)(d & 255);
    }
}

// ---- pass C — per-bucket fine CSR: row_ptr + u16 csr_src (L2-window stores) ----
__global__ __launch_bounds__(256) void bucket_csr_k(const unsigned* __restrict__ bbuf,
                                                    const int* __restrict__ bkt_base,
                                                    int* __restrict__ row_ptr,
                                                    u16* __restrict__ csr_src) {
    __shared__ int hist[256], scan[256], cur[256];
    int b = blockIdx.x, t = threadIdx.x;
    int e0 = bkt_base[b], e1 = bkt_base[b + 1];
    hist[t] = 0;
    __syncthreads();
    for (int e = e0 + t; e < e1; e += 256)
        atomicAdd(&hist[bbuf[e] & 255], 1);
    __syncthreads();
    int v = hist[t];
    scan[t] = v;
    __syncthreads();
    for (int off = 1; off < 256; off <<= 1) {
        int x = (t >= off) ? scan[t - off] : 0;
        __syncthreads();
        scan[t] += x;
        __syncthreads();
    }
    int ex = scan[t] - v;  // exclusive
    int n = b * 256 + t;
    if (n < NN) row_ptr[n] = e0 + ex;
    cur[t] = e0 + ex;
    __syncthreads();
    for (int e = e0 + t; e < e1; e += 256) {
        unsigned p = bbuf[e];
        int pos = atomicAdd(&cur[p & 255], 1);
        csr_src[pos] = (u16)(p >> 8);
    }
    if (b == 0 && t == 0) row_ptr[NN] = EP;
}

// ---- MFMA GEMM: C[M=NN][N] bf16 = A[NN][K] bf16 @ Wt[N][K] bf16 (f32 acc) ----
template <int K, int N>
__global__ __launch_bounds__(256) void gemm_mfma_k(
    const u16* __restrict__ A, const u16* __restrict__ Wt, u16* __restrict__ C) {
    constexpr int NT = N / 16, KS = K / 32;
    const int wave = threadIdx.x >> 6, lane = threadIdx.x & 63;
    const int quad = lane >> 4, l15 = lane & 15;
    const int m0 = blockIdx.x * 64 + wave * 16;
    int rowA = m0 + l15;
    if (rowA >= NN) rowA = NN - 1;
    const u16* aptr = A + (size_t)rowA * K + quad * 8;
    const u16* bptr = Wt + (size_t)l15 * K + quad * 8;
    f32x4 acc[NT] = {};
#pragma unroll
    for (int ks = 0; ks < KS; ++ks) {
        bf16x8 af = *(const bf16x8*)(aptr + ks * 32);
        bf16x8 bf[NT];
#pragma unroll
        for (int nt = 0; nt < NT; ++nt)
            bf[nt] = *(const bf16x8*)(bptr + (size_t)nt * 16 * K + ks * 32);
#pragma unroll
        for (int nt = 0; nt < NT; ++nt)
            acc[nt] = __builtin_amdgcn_mfma_f32_16x16x32_bf16(af, bf[nt], acc[nt], 0, 0, 0);
    }
#pragma unroll
    for (int nt = 0; nt < NT; ++nt) {
#pragma unroll
        for (int reg = 0; reg < 4; ++reg) {
            int row = m0 + quad * 4 + reg;
            if (row < NN) C[(size_t)row * N + nt * 16 + l15] = f2b(acc[nt][reg]);
        }
    }
}

// ---- per-node attention scores (bf16 h): one 64-lane wave per head ----
__global__ void att_scores_k(const u16* __restrict__ h, const float* __restrict__ asrc,
                             const float* __restrict__ adst, float* __restrict__ a_s,
                             float* __restrict__ a_d, int H) {
    int n = blockIdx.x, tid = threadIdx.x;  // blockDim.x == H*64
    float v = b2f(h[(size_t)n * blockDim.x + tid]);
    float ps = v * asrc[tid];
    float pd = v * adst[tid];
#pragma unroll
    for (int off = 32; off; off >>= 1) {
        ps += __shfl_down(ps, off);
        pd += __shfl_down(pd, off);
    }
    if ((tid & 63) == 0) {
        int hh = tid >> 6;
        a_s[(size_t)n * H + hh] = ps;
        a_d[(size_t)n * H + hh] = pd;
    }
}

// ---- fused gather (bf16 h): one WAVE per node; VEC = CH/64 bf16 per lane ----
// Lane-parallel exp, JB-batched j-loop (8 independent loads in flight).
template <int CH, int H, bool HEAD>
__global__ __launch_bounds__(256) void gat_gather_k(
    const int* __restrict__ row_ptr, const u16* __restrict__ csr_src,
    const float* __restrict__ a_s, const float* __restrict__ a_d,
    const u16* __restrict__ h, const float* __restrict__ bias,
    u16* __restrict__ outg, const float* __restrict__ Wl,
    const float* __restrict__ bl, float* __restrict__ outh) {
    constexpr int VEC = CH / 64;
    constexpr int JB = 8;
    int n = (blockIdx.x * blockDim.x + threadIdx.x) >> 6;  // global wave id = node
    int lane = threadIdx.x & 63;
    if (n >= NN) return;  // wave-uniform exit
    int r0 = row_ptr[n], r1 = row_ptr[n + 1];
    const bool hi = (VEC == 2) ? (lane >= 32) : false;
    const u16* hlane = h + lane * VEC;

    float adn[H];
#pragma unroll
    for (int hh = 0; hh < H; ++hh) adn[hh] = a_d[n * H + hh];

    float dh0 = 0.f, dh1 = 0.f;
    float acc[VEC];
#pragma unroll
    for (int v = 0; v < VEC; ++v) acc[v] = 0.f;

    for (int base = r0; base < r1; base += 64) {
        int cnt = min(64, r1 - base);
        int idx = base + lane;
        bool act = idx < r1;
        int sl = act ? (int)csr_src[idx] : 0;
        float exl0 = 0.f, exl1 = 0.f;
        {
            float e = a_s[sl * H + 0] + adn[0];
            e = e > 0.f ? e : 0.2f * e;
            e = fminf(e, 60.f);
            exl0 = act ? __expf(e) : 0.f;
            dh0 += exl0;
        }
        if (H == 2) {
            float e = a_s[sl * H + 1] + adn[1];
            e = e > 0.f ? e : 0.2f * e;
            e = fminf(e, 60.f);
            exl1 = act ? __expf(e) : 0.f;
            dh1 += exl1;
        }
        for (int j0 = 0; j0 < cnt; j0 += JB) {
            int ss[JB];
            float exv[JB];
#pragma unroll
            for (int i = 0; i < JB; ++i) {
                int j = j0 + i;
                ss[i] = __shfl(sl, j);
                if (H == 1) {
                    exv[i] = __shfl(exl0, j);
                } else {
                    float e0 = __shfl(exl0, j);
                    float e1 = __shfl(exl1, j);
                    exv[i] = hi ? e1 : e0;
                }
            }
            if (VEC == 2) {
                ushort2 hv[JB];
#pragma unroll
                for (int i = 0; i < JB; ++i)
                    hv[i] = *(const ushort2*)(hlane + (size_t)ss[i] * CH);
#pragma unroll
                for (int i = 0; i < JB; ++i) {
                    acc[0] += exv[i] * b2f(hv[i].x);
                    acc[1] += exv[i] * b2f(hv[i].y);
                }
            } else {
                u16 hv[JB];
#pragma unroll
                for (int i = 0; i < JB; ++i)
                    hv[i] = hlane[(size_t)ss[i] * CH];
#pragma unroll
                for (int i = 0; i < JB; ++i)
                    acc[0] += exv[i] * b2f(hv[i]);
            }
        }
    }

#pragma unroll
    for (int off = 32; off; off >>= 1) dh0 += __shfl_xor(dh0, off);
    float dn = dh0;
    if (H == 2) {
#pragma unroll
        for (int off = 32; off; off >>= 1) dh1 += __shfl_xor(dh1, off);
        dn = hi ? dh1 : dh0;
    }

    if (VEC == 2) {
        int c = lane * 2;
        float2 bv = *(const float2*)(bias + c);
        float v0 = acc[0] / dn + bv.x;
        float v1 = acc[1] / dn + bv.y;
        v0 = v0 > 0.f ? v0 : expm1f(v0);
        v1 = v1 > 0.f ? v1 : expm1f(v1);
        ushort2 ov;
        ov.x = f2b(v0); ov.y = f2b(v1);
        *(ushort2*)(outg + (size_t)n * CH + c) = ov;
    } else {
        float v0 = acc[0] / dn + bias[lane];
        v0 = v0 > 0.f ? v0 : expm1f(v0);
        if (HEAD) {
#pragma unroll
            for (int cls = 0; cls < NCLS; ++cls) {
                float p = v0 * Wl[lane * NCLS + cls];
#pragma unroll
                for (int off = 32; off; off >>= 1) p += __shfl_xor(p, off);
                if (lane == cls) outh[(size_t)n * NCLS + cls] = p + bl[cls];
            }
        } else {
            outg[(size_t)n * CH + lane] = f2b(v0);
        }
    }
}

extern "C" void kernel_launch(void* const* d_in, const int* in_sizes, int n_in,
                              void* d_out, int out_size, void* d_ws, size_t ws_size,
                              hipStream_t stream) {
    const float* x   = (const float*)d_in[0];
    const int*   ei  = (const int*)d_in[1];
    const float* W1  = (const float*)d_in[2];
    const float* as1 = (const float*)d_in[3];
    const float* ad1 = (const float*)d_in[4];
    const float* b1  = (const float*)d_in[5];
    const float* W2  = (const float*)d_in[6];
    const float* as2 = (const float*)d_in[7];
    const float* ad2 = (const float*)d_in[8];
    const float* b2  = (const float*)d_in[9];
    const float* Wl  = (const float*)d_in[10];
    const float* bl  = (const float*)d_in[11];
    float* out = (float*)d_out;

    // ---- workspace layout: ~56 MB (bbuf overlays g1 — consumed before g1 written) ----
    float* ws = (float*)d_ws;
    size_t o = 0;
    u16* xb  = (u16*)(ws + o); o += (size_t)NN * 128;   // bf16 x [NN][256]
    u16* hb  = (u16*)(ws + o); o += (size_t)NN * 64;    // bf16 h1[NN][128] / h2[NN][64]
    u16* g1  = (u16*)(ws + o); o += (size_t)NN * 64;    // bf16 g1 [NN][128]  (= bbuf space)
    unsigned* bbuf = (unsigned*)g1;                      // EP u32 = 6.6 MB < 12.8 MB ✓
    u16* w1t = (u16*)(ws + o); o += 128 * 256 / 2;      // bf16 W1^T [128][256]
    u16* w2t = (u16*)(ws + o); o += 64 * 128 / 2;       // bf16 W2^T [64][128]
    float* a_s = ws + o;       o += (size_t)NN * 2;
    float* a_d = ws + o;       o += (size_t)NN * 2;
    int* ints = (int*)(ws + o);
    size_t io = 0;
    int* gcnt     = ints + io; io += NBKT;
    int* bkt_base = ints + io; io += NBKT + 1;
    int* gcursor  = ints + io; io += NBKT;
    int* row_ptr  = ints + io; io += NN + 1;
    u16* csr_src  = (u16*)(ints + io); io += (EP + 1) / 2;
    int* mode     = ints + io; io += 1;

    detect_mode_k<<<1, 64, 0, stream>>>(ei, mode);

    // ---- converts ----
    xcvt_k<<<((size_t)NN * 64 + 255) / 256, 256, 0, stream>>>(x, xb, NN * 64);
    wcvt_k<<<(256 * 128 + 255) / 256, 256, 0, stream>>>(W1, w1t, 256, 128);
    wcvt_k<<<(128 * 64 + 255) / 256, 256, 0, stream>>>(W2, w2t, 128, 64);

    // ---- radix CSR build ----
    hipMemsetAsync(gcnt, 0, NBKT * sizeof(int), stream);
    bktcount_k<<<NPB, 256, 0, stream>>>(ei, mode, gcnt);
    bktscan_k<<<1, 256, 0, stream>>>(gcnt, bkt_base, gcursor);
    partition_k<<<NPB, 256, 0, stream>>>(ei, mode, gcursor, bbuf);
    bucket_csr_k<<<NBKT, 256, 0, stream>>>(bbuf, bkt_base, row_ptr, csr_src);

    const int gatherBlocks = (NN + 3) / 4;  // 4 waves (nodes) per 256-thread block
    const int gemmBlocks = (NN + 63) / 64;

    // ---- layer 1: GATConv(256 -> 64, heads=2, concat) + ELU ----
    gemm_mfma_k<256, 128><<<gemmBlocks, 256, 0, stream>>>(xb, w1t, hb);   // h1 bf16
    att_scores_k<<<NN, 128, 0, stream>>>(hb, as1, ad1, a_s, a_d, 2);
    gat_gather_k<128, 2, false><<<gatherBlocks, 256, 0, stream>>>(
        row_ptr, csr_src, a_s, a_d, hb, b1, g1, nullptr, nullptr, nullptr);

    // ---- layer 2: GATConv(128 -> 64, heads=1) + ELU + fused head ----
    gemm_mfma_k<128, 64><<<gemmBlocks, 256, 0, stream>>>(g1, w2t, hb);    // h2 bf16
    att_scores_k<<<NN, 64, 0, stream>>>(hb, as2, ad2, a_s, a_d, 1);
    gat_gather_k<64, 1, true><<<gatherBlocks, 256, 0, stream>>>(
        row_ptr, csr_src, a_s, a_d, hb, b2, nullptr, Wl, bl, out);
}